// Round 8
// baseline (729.157 us; speedup 1.0000x reference)
//
#include <hip/hip_runtime.h>
#include <stdint.h>
#include <stddef.h>

// Problem constants
#define B_    2
#define S_    2048
#define HID_  2048
#define H_    16
#define NOPE_ 128
#define ROPE_ 64
#define VD_   128
#define RANK_ 512
#define QD_   192          // NOPE+ROPE
#define M_    4096         // B*S
#define NEGV  (-1e9f)

typedef __attribute__((ext_vector_type(8))) __bf16 bf16x8;
typedef __attribute__((ext_vector_type(8))) short  short8;
typedef __attribute__((ext_vector_type(4))) short  short4v;
typedef __attribute__((ext_vector_type(4))) float  f32x4;

__device__ __forceinline__ short f2bf(float f) {   // f32 -> bf16 bits, RNE
  uint32_t u = __builtin_bit_cast(uint32_t, f);
  u += 0x7fffu + ((u >> 16) & 1u);
  return (short)(u >> 16);
}

__device__ __forceinline__ void gll16(const void* g, void* l) {
  // async global->LDS, 16B/lane; LDS dest = wave-uniform base + lane*16
  __builtin_amdgcn_global_load_lds(
      (__attribute__((address_space(1))) void*)(g),
      (__attribute__((address_space(3))) void*)(l), 16, 0, 0);
}

__device__ __forceinline__ f32x4 mfma16(short8 a, short8 b, f32x4 c) {
  return __builtin_amdgcn_mfma_f32_16x16x32_bf16(
      __builtin_bit_cast(bf16x8, a), __builtin_bit_cast(bf16x8, b), c, 0, 0, 0);
}

// ---------------- cast kernels ----------------
__global__ void k_cast4(const float* __restrict__ in, short* __restrict__ out, int n4) {
  int i = blockIdx.x * blockDim.x + threadIdx.x;
  if (i >= n4) return;
  float4 v = *(const float4*)(in + (size_t)i * 4);
  short4v o = { f2bf(v.x), f2bf(v.y), f2bf(v.z), f2bf(v.w) };
  *(short4v*)(out + (size_t)i * 4) = o;
}

// kv_a_proj_w (576 x 2048) -> padded (640 x 2048) bf16, zero rows 576..639
__global__ void k_cast_kva(const float* __restrict__ in, short* __restrict__ out) {
  int i = blockIdx.x * blockDim.x + threadIdx.x;   // per 4 elems
  int e = i * 4;
  int r = e >> 11, c = e & 2047;
  short4v o = {0, 0, 0, 0};
  if (r < 576) {
    float4 v = *(const float4*)(in + (size_t)r * 2048 + c);
    o[0] = f2bf(v.x); o[1] = f2bf(v.y); o[2] = f2bf(v.z); o[3] = f2bf(v.w);
  }
  *(short4v*)(out + e) = o;
}

// ---------------- GEMM: C[M,N] = A[M,K] * B[N,K]^T (bf16 in, f32 acc) --------
// 128x128 tile, BK=64, 4 waves (2x2), each wave 64x64 = 4x4 16x16x32 frags.
// LDS XOR-swizzle on 16B chunks: position p holds logical chunk p ^ (row&7).
template <typename OutT>
__global__ __launch_bounds__(256) void k_gemm_bt(
    const short* __restrict__ A, const short* __restrict__ Bm,
    OutT* __restrict__ C, int M, int N, int K)
{
  __shared__ __align__(16) short As[128 * 64];
  __shared__ __align__(16) short Bs[128 * 64];
  const int tid = threadIdx.x;
  const int lane = tid & 63, wid = tid >> 6;
  const int l15 = lane & 15, lhi = lane >> 4;
  const int brow = blockIdx.y * 128, bcol = blockIdx.x * 128;
  const int wr = (wid >> 1) * 64, wc = (wid & 1) * 64;

  f32x4 acc[4][4];
#pragma unroll
  for (int i = 0; i < 4; ++i)
#pragma unroll
    for (int j = 0; j < 4; ++j) acc[i][j] = (f32x4)0.f;

  const int srow = lane >> 3;                 // 0..7 within 8-row segment
  const int scol = ((lane & 7) ^ srow) * 8;   // inverse-swizzled global col

  for (int k0 = 0; k0 < K; k0 += 64) {
    __syncthreads();
#pragma unroll
    for (int i = 0; i < 4; ++i) {
      int seg = wid * 4 + i;                  // 16 segments of 1KB
      int row = seg * 8 + srow;               // row&7 == srow
      gll16(A  + (size_t)(brow + row) * K + k0 + scol, &As[seg * 512]);
      gll16(Bm + (size_t)(bcol + row) * K + k0 + scol, &Bs[seg * 512]);
    }
    __syncthreads();
#pragma unroll
    for (int ks = 0; ks < 2; ++ks) {
      short8 af[4], bfr[4];
#pragma unroll
      for (int i = 0; i < 4; ++i) {
        int r = wr + i * 16 + l15;            // r&7 == l15&7
        af[i] = *(const short8*)&As[r * 64 + (((ks * 4 + lhi) ^ (l15 & 7)) << 3)];
      }
#pragma unroll
      for (int j = 0; j < 4; ++j) {
        int r = wc + j * 16 + l15;
        bfr[j] = *(const short8*)&Bs[r * 64 + (((ks * 4 + lhi) ^ (l15 & 7)) << 3)];
      }
#pragma unroll
      for (int i = 0; i < 4; ++i)
#pragma unroll
        for (int j = 0; j < 4; ++j) acc[i][j] = mfma16(af[i], bfr[j], acc[i][j]);
    }
  }
  // epilogue: C/D layout col=lane&15, row=(lane>>4)*4+reg  [m89-verified]
#pragma unroll
  for (int i = 0; i < 4; ++i) {
    int r0 = brow + wr + i * 16 + lhi * 4;
#pragma unroll
    for (int j = 0; j < 4; ++j) {
      int c = bcol + wc + j * 16 + l15;
#pragma unroll
      for (int t = 0; t < 4; ++t) {
        float v = acc[i][j][t];
        if constexpr (__is_same(OutT, float)) C[(size_t)(r0 + t) * N + c] = v;
        else                                  C[(size_t)(r0 + t) * N + c] = f2bf(v);
      }
    }
  }
}

// ---------------- RMSNorm + split (f32 math) ----------------
__global__ __launch_bounds__(256) void k_rms(
    const float* __restrict__ comp,   // M x 640 (cols 0..511 latent, 512..575 rope)
    const float* __restrict__ w,      // 512
    short* __restrict__ normed,       // M x 512 bf16
    short* __restrict__ krot)         // M x 64  bf16
{
  __shared__ float red[4];
  const int row = blockIdx.x, tid = threadIdx.x;
  const float* x = comp + (size_t)row * 640;
  float v0 = x[tid], v1 = x[tid + 256];
  float ss = v0 * v0 + v1 * v1;
#pragma unroll
  for (int off = 1; off < 64; off <<= 1) ss += __shfl_xor(ss, off);
  if ((tid & 63) == 0) red[tid >> 6] = ss;
  __syncthreads();
  float rs = rsqrtf((red[0] + red[1] + red[2] + red[3]) * (1.f / 512.f) + 1e-6f);
  normed[(size_t)row * 512 + tid]       = f2bf(w[tid] * v0 * rs);
  normed[(size_t)row * 512 + tid + 256] = f2bf(w[tid + 256] * v1 * rs);
  if (tid < 64) krot[(size_t)row * 64 + tid] = f2bf(x[512 + tid]);
}

// ---------------- V transpose: kv(M,4096) V-half -> vt (B*H, 128, 2048) -----
__global__ __launch_bounds__(256) void k_vtrans(
    const short* __restrict__ kv, short* __restrict__ vt)
{
  __shared__ __align__(16) short t[64][136];   // 272B rows: 16B-aligned
  const int tid = threadIdx.x;
  const int st = blockIdx.x, bh = blockIdx.y;
  const int b = bh >> 4, h = bh & 15;
  const int s0 = st * 64;
#pragma unroll
  for (int i = 0; i < 4; ++i) {
    int e8 = i * 256 + tid;
    int r = e8 >> 4, c = (e8 & 15) * 8;
    short8 v = *(const short8*)&kv[(size_t)(b * S_ + s0 + r) * 4096 + h * 256 + 128 + c];
    *(short8*)&t[r][c] = v;
  }
  __syncthreads();
#pragma unroll
  for (int i = 0; i < 4; ++i) {
    int e8 = i * 256 + tid;
    int d = e8 >> 3, sc = (e8 & 7) * 8;
    short8 o;
#pragma unroll
    for (int k = 0; k < 8; ++k) o[k] = t[sc + k][d];
    *(short8*)&vt[((size_t)bh * 128 + d) * S_ + s0 + sc] = o;
  }
}

// ---------------- causal flash attention (128 q-rows / 8 waves) ----------------
// T14 async-STAGE split: K/V for tile t+1 loaded to REGISTERS during tile t's
// compute; ds_write at top of t+1. Exposed staging cost per tile becomes the
// ds_write, not the HBM/L2 latency. Barriers per tile:
//   B0 __syncthreads  : implicit vmcnt(0) = consume-wait for tile-old loads (free)
//   B1 raw s_barrier  : after lgkmcnt(0); does NOT drain the new prefetch
//   (mid-tile barrier removed: Ps rows are wave-private)
__global__ __launch_bounds__(512, 4) void k_attn(
    const short* __restrict__ q,     // M x 3072  (h*192 + d)
    const short* __restrict__ kv,    // M x 4096  (h*256 + c), c<128 = k_pass
    const short* __restrict__ krot,  // M x 64
    const short* __restrict__ vt,    // (B*H*128) x 2048  (V^T)
    short* __restrict__ outp)        // M x 2048  (h*128 + d)
{
  __shared__ __align__(16) short Kp[64 * 128];
  __shared__ __align__(16) short Kr[64 * 64];
  __shared__ __align__(16) short Vt[128 * 64];
  __shared__ __align__(16) short Ps[128 * 64];

  const int tid = threadIdx.x, lane = tid & 63, wid = tid >> 6;
  const int l15 = lane & 15, lhi = lane >> 4;
  // XCD-co-locating decode: XCD k gets blocks o==k (mod 8) -> bh in [4k,4k+4).
  // Within each bh, qtb descending (LPT).
  const int o = blockIdx.x;
  const int w = (o & 7) * 64 + (o >> 3);
  const int bh = w >> 4;
  const int qtb = 15 - (w & 15);
  const int b = bh >> 4, h = bh & 15;
  const int q0 = qtb * 128;
  const int ktmax = 2 * qtb + 1;

  const int sr8 = lane >> 3;
  const int sc8 = ((lane & 7) ^ sr8) * 8;

  // ---- reg-staged prefetch (T14) ----
  short8 rKp0, rKp1, rKr, rVt0, rVt1;
  const int kpRow  = wid * 8 + (lane >> 4);          // seg(wid*2)*4 + lane>>4
  const int kpCol0 = ((lane & 15) ^ (kpRow & 7)) * 8;
  const int kpRow1 = kpRow + 4;                      // seg(wid*2+1)*4 + lane>>4
  const int kpCol1 = ((lane & 15) ^ (kpRow1 & 7)) * 8;
  const int krRow  = wid * 8 + sr8;
  const int vtD0   = wid * 16 + sr8;                 // seg(wid*2)*8 + sr8
  const int vtD1   = vtD0 + 8;

  auto LOADR = [&](int kt) {
    const int krow0 = b * S_ + kt * 64;
    rKp0 = *(const short8*)(kv + (size_t)(krow0 + kpRow) * 4096 + h * 256 + kpCol0);
    rKp1 = *(const short8*)(kv + (size_t)(krow0 + kpRow1) * 4096 + h * 256 + kpCol1);
    rKr  = *(const short8*)(krot + (size_t)(krow0 + krRow) * 64 + sc8);
    rVt0 = *(const short8*)(vt + ((size_t)bh * 128 + vtD0) * S_ + kt * 64 + sc8);
    rVt1 = *(const short8*)(vt + ((size_t)bh * 128 + vtD1) * S_ + kt * 64 + sc8);
  };
  auto WRITES = [&]() {
    *(short8*)&Kp[(wid * 2) * 512 + lane * 8]     = rKp0;
    *(short8*)&Kp[(wid * 2 + 1) * 512 + lane * 8] = rKp1;
    *(short8*)&Kr[wid * 512 + lane * 8]           = rKr;
    *(short8*)&Vt[(wid * 2) * 512 + lane * 8]     = rVt0;
    *(short8*)&Vt[(wid * 2 + 1) * 512 + lane * 8] = rVt1;
  };

  // Q A-frags: wave strip = wid*16 rows; row-in-strip = l15; k-chunk = lhi*8
  short8 qf[6];
  {
    const short* qp = q + (size_t)(b * S_ + q0 + wid * 16 + l15) * (H_ * QD_) + h * QD_ + lhi * 8;
#pragma unroll
    for (int ks = 0; ks < 6; ++ks) qf[ks] = *(const short8*)(qp + ks * 32);
  }

  float m_run[4] = {-1e30f, -1e30f, -1e30f, -1e30f};
  float l_run[4] = {0.f, 0.f, 0.f, 0.f};
  f32x4 oa[8];
#pragma unroll
  for (int j = 0; j < 8; ++j) oa[j] = (f32x4)0.f;

  const float scale = 0.07216878f;   // 192^-0.5

  LOADR(0);                          // prologue: issue tile-0 loads

  for (int kt = 0; kt <= ktmax; ++kt) {
    // B0: implicit vmcnt(0)+lgkmcnt(0) waits for the prefetched regs (issued a
    // full tile ago -> latency already hidden) and orders prev-tile LDS reads.
    __syncthreads();
    WRITES();                                   // ds_write this tile's K/V
    asm volatile("s_waitcnt lgkmcnt(0)" ::: "memory");  // my writes complete
    if (kt < ktmax) LOADR(kt + 1);              // issue next prefetch (stays in flight)
    __builtin_amdgcn_s_barrier();               // B1: all writes visible; NO vmcnt drain
    __builtin_amdgcn_sched_barrier(0);

    // waves entirely below this tile's k-range skip compute (barriers kept)
    const bool active = (kt * 64) <= (q0 + wid * 16 + 15);

    if (active) {
      // ---- S = Q K^T ----
      f32x4 sf[4];
#pragma unroll
      for (int fc = 0; fc < 4; ++fc) sf[fc] = (f32x4)0.f;
#pragma unroll
      for (int fc = 0; fc < 4; ++fc) {
        int n = fc * 16 + l15, nx = n & 7;
#pragma unroll
        for (int ks = 0; ks < 4; ++ks) {
          short8 kf = *(const short8*)&Kp[n * 128 + (((ks * 4 + lhi) ^ nx) << 3)];
          sf[fc] = mfma16(qf[ks], kf, sf[fc]);
        }
#pragma unroll
        for (int ks = 4; ks < 6; ++ks) {
          short8 kf = *(const short8*)&Kr[n * 64 + ((((ks - 4) * 4 + lhi) ^ nx) << 3)];
          sf[fc] = mfma16(qf[ks], kf, sf[fc]);
        }
      }
      // scale + causal mask (only near-diagonal tiles need the compare)
      if (kt * 64 + 63 > q0 + wid * 16) {
#pragma unroll
        for (int fc = 0; fc < 4; ++fc) {
          int kl = kt * 64 + fc * 16 + l15;
#pragma unroll
          for (int r = 0; r < 4; ++r) {
            int ql = q0 + wid * 16 + lhi * 4 + r;
            sf[fc][r] = (kl <= ql) ? sf[fc][r] * scale : NEGV;
          }
        }
      } else {
#pragma unroll
        for (int fc = 0; fc < 4; ++fc)
#pragma unroll
          for (int r = 0; r < 4; ++r) sf[fc][r] *= scale;
      }
      // ---- online softmax (f32) ----
      float mnew[4], scf[4], rsum[4];
#pragma unroll
      for (int r = 0; r < 4; ++r) {
        float t = fmaxf(fmaxf(sf[0][r], sf[1][r]), fmaxf(sf[2][r], sf[3][r]));
#pragma unroll
        for (int off = 1; off < 16; off <<= 1) t = fmaxf(t, __shfl_xor(t, off));
        mnew[r] = fmaxf(m_run[r], t);
        scf[r] = __expf(m_run[r] - mnew[r]);
        m_run[r] = mnew[r];
        rsum[r] = 0.f;
      }
#pragma unroll
      for (int fc = 0; fc < 4; ++fc)
#pragma unroll
        for (int r = 0; r < 4; ++r) {
          float p = __expf(sf[fc][r] - mnew[r]);
          sf[fc][r] = p;
          rsum[r] += p;
        }
#pragma unroll
      for (int r = 0; r < 4; ++r) {
        float t = rsum[r];
#pragma unroll
        for (int off = 1; off < 16; off <<= 1) t += __shfl_xor(t, off);
        l_run[r] = l_run[r] * scf[r] + t;
      }
#pragma unroll
      for (int j = 0; j < 8; ++j)
#pragma unroll
        for (int r = 0; r < 4; ++r) oa[j][r] *= scf[r];
      // write P (bf16) to LDS, swizzled (rows are WAVE-PRIVATE)
#pragma unroll
      for (int fc = 0; fc < 4; ++fc)
#pragma unroll
        for (int r = 0; r < 4; ++r) {
          int pr = wid * 16 + lhi * 4 + r;
          int pc = fc * 16 + l15;
          Ps[pr * 64 + ((((pc >> 3) ^ (pr & 7)) << 3) | (pc & 7))] = f2bf(sf[fc][r]);
        }
      // wave-local fence only: Ps rows are private to this wave, no block barrier
      asm volatile("s_waitcnt lgkmcnt(0)" ::: "memory");
      __builtin_amdgcn_sched_barrier(0);
      // ---- O += P V ----
      short8 pa[2];
      {
        int prow = wid * 16 + l15, px = prow & 7;
#pragma unroll
        for (int ks = 0; ks < 2; ++ks)
          pa[ks] = *(const short8*)&Ps[prow * 64 + (((ks * 4 + lhi) ^ px) << 3)];
      }
#pragma unroll
      for (int j = 0; j < 8; ++j) {
        int d = j * 16 + l15, dx = d & 7;
#pragma unroll
        for (int ks = 0; ks < 2; ++ks) {
          short8 vb = *(const short8*)&Vt[d * 64 + (((ks * 4 + lhi) ^ dx) << 3)];
          oa[j] = mfma16(pa[ks], vb, oa[j]);
        }
      }
    }
  }
  // epilogue: normalize and store bf16
#pragma unroll
  for (int j = 0; j < 8; ++j)
#pragma unroll
    for (int r = 0; r < 4; ++r) {
      size_t row = (size_t)(b * S_ + q0 + wid * 16 + lhi * 4 + r);
      int col = h * 128 + j * 16 + l15;
      outp[row * 2048 + col] = f2bf(oa[j][r] / l_run[r]);
    }
}

// ---------------- launch ----------------
extern "C" void kernel_launch(void* const* d_in, const int* in_sizes, int n_in,
                              void* d_out, int out_size, void* d_ws, size_t ws_size,
                              hipStream_t stream) {
  const float* hidden = (const float*)d_in[0];
  const float* qw     = (const float*)d_in[1];
  const float* kvaw   = (const float*)d_in[2];
  const float* lnw    = (const float*)d_in[3];
  const float* kvbw   = (const float*)d_in[4];
  const float* ow     = (const float*)d_in[5];

  char* ws = (char*)d_ws;
  short* hidb  = (short*)(ws + 0);           // 4096x2048 bf16   16.78MB
  short* qwb   = (short*)(ws + 16777216);    // 3072x2048        12.58MB
  short* kvawb = (short*)(ws + 29360128);    // 640x2048 (pad)    2.62MB
  short* kvbwb = (short*)(ws + 31981568);    // 4096x512          4.19MB
  short* owb   = (short*)(ws + 36175872);    // 2048x2048         8.39MB
  short* qb    = (short*)(ws + 44564480);    // 4096x3072        25.17MB
  float* comp  = (float*)(ws + 69730304);    // 4096x640 f32     10.49MB
  short* normb = (short*)(ws + 80216064);    // 4096x512          4.19MB
  short* krotb = (short*)(ws + 84410368);    // 4096x64           0.52MB
  short* kvb   = (short*)(ws + 84934656);    // 4096x4096        33.55MB
  short* vtb   = (short*)(ws + 118489088);   // 32x128x2048      16.78MB
  short* attnb = (short*)(ws + 135266304);   // 4096x2048        16.78MB

  // casts
  k_cast4<<<8192, 256, 0, stream>>>(hidden, hidb, 2097152);
  k_cast4<<<6144, 256, 0, stream>>>(qw, qwb, 1572864);
  k_cast_kva<<<1280, 256, 0, stream>>>(kvaw, kvawb);
  k_cast4<<<2048, 256, 0, stream>>>(kvbw, kvbwb, 524288);
  k_cast4<<<4096, 256, 0, stream>>>(ow, owb, 1048576);

  // projections
  k_gemm_bt<short><<<dim3(24, 32), 256, 0, stream>>>(hidb, qwb, qb, M_, 3072, 2048);
  k_gemm_bt<float><<<dim3(5, 32), 256, 0, stream>>>(hidb, kvawb, comp, M_, 640, 2048);
  k_rms<<<4096, 256, 0, stream>>>(comp, lnw, normb, krotb);
  k_gemm_bt<short><<<dim3(32, 32), 256, 0, stream>>>(normb, kvbwb, kvb, M_, 4096, 512);
  k_vtrans<<<dim3(32, 32), 256, 0, stream>>>(kvb, vtb);

  // attention: 512 blocks x 512 threads (8 waves, 128 q-rows each)
  k_attn<<<512, 512, 0, stream>>>(qb, kvb, krotb, vtb, attnb);

  // output projection
  k_gemm_bt<float><<<dim3(16, 32), 256, 0, stream>>>(attnb, owb, (float*)d_out, M_, 2048, 2048);
}

// Round 9
// 482.682 us; speedup vs baseline: 1.5106x; 1.5106x over previous
//
#include <hip/hip_runtime.h>
#include <stdint.h>
#include <stddef.h>

// Problem constants
#define B_    2
#define S_    2048
#define HID_  2048
#define H_    16
#define NOPE_ 128
#define ROPE_ 64
#define VD_   128
#define RANK_ 512
#define QD_   192          // NOPE+ROPE
#define M_    4096         // B*S
#define NEGV  (-1e9f)

typedef __attribute__((ext_vector_type(8))) __bf16 bf16x8;
typedef __attribute__((ext_vector_type(8))) short  short8;
typedef __attribute__((ext_vector_type(4))) short  short4v;
typedef __attribute__((ext_vector_type(4))) float  f32x4;

__device__ __forceinline__ short f2bf(float f) {   // f32 -> bf16 bits, RNE
  uint32_t u = __builtin_bit_cast(uint32_t, f);
  u += 0x7fffu + ((u >> 16) & 1u);
  return (short)(u >> 16);
}

__device__ __forceinline__ void gll16(const void* g, void* l) {
  // async global->LDS, 16B/lane; LDS dest = wave-uniform base + lane*16
  __builtin_amdgcn_global_load_lds(
      (__attribute__((address_space(1))) void*)(g),
      (__attribute__((address_space(3))) void*)(l), 16, 0, 0);
}

__device__ __forceinline__ f32x4 mfma16(short8 a, short8 b, f32x4 c) {
  return __builtin_amdgcn_mfma_f32_16x16x32_bf16(
      __builtin_bit_cast(bf16x8, a), __builtin_bit_cast(bf16x8, b), c, 0, 0, 0);
}

// ---------------- cast kernels ----------------
__global__ void k_cast4(const float* __restrict__ in, short* __restrict__ out, int n4) {
  int i = blockIdx.x * blockDim.x + threadIdx.x;
  if (i >= n4) return;
  float4 v = *(const float4*)(in + (size_t)i * 4);
  short4v o = { f2bf(v.x), f2bf(v.y), f2bf(v.z), f2bf(v.w) };
  *(short4v*)(out + (size_t)i * 4) = o;
}

// kv_a_proj_w (576 x 2048) -> padded (640 x 2048) bf16, zero rows 576..639
__global__ void k_cast_kva(const float* __restrict__ in, short* __restrict__ out) {
  int i = blockIdx.x * blockDim.x + threadIdx.x;   // per 4 elems
  int e = i * 4;
  int r = e >> 11, c = e & 2047;
  short4v o = {0, 0, 0, 0};
  if (r < 576) {
    float4 v = *(const float4*)(in + (size_t)r * 2048 + c);
    o[0] = f2bf(v.x); o[1] = f2bf(v.y); o[2] = f2bf(v.z); o[3] = f2bf(v.w);
  }
  *(short4v*)(out + e) = o;
}

// ---------------- GEMM: C[M,N] = A[M,K] * B[N,K]^T (bf16 in, f32 acc) --------
// 128x128 tile, BK=64, 4 waves (2x2), each wave 64x64 = 4x4 16x16x32 frags.
// LDS XOR-swizzle on 16B chunks: position p holds logical chunk p ^ (row&7).
template <typename OutT>
__global__ __launch_bounds__(256) void k_gemm_bt(
    const short* __restrict__ A, const short* __restrict__ Bm,
    OutT* __restrict__ C, int M, int N, int K)
{
  __shared__ __align__(16) short As[128 * 64];
  __shared__ __align__(16) short Bs[128 * 64];
  const int tid = threadIdx.x;
  const int lane = tid & 63, wid = tid >> 6;
  const int l15 = lane & 15, lhi = lane >> 4;
  const int brow = blockIdx.y * 128, bcol = blockIdx.x * 128;
  const int wr = (wid >> 1) * 64, wc = (wid & 1) * 64;

  f32x4 acc[4][4];
#pragma unroll
  for (int i = 0; i < 4; ++i)
#pragma unroll
    for (int j = 0; j < 4; ++j) acc[i][j] = (f32x4)0.f;

  const int srow = lane >> 3;                 // 0..7 within 8-row segment
  const int scol = ((lane & 7) ^ srow) * 8;   // inverse-swizzled global col

  for (int k0 = 0; k0 < K; k0 += 64) {
    __syncthreads();
#pragma unroll
    for (int i = 0; i < 4; ++i) {
      int seg = wid * 4 + i;                  // 16 segments of 1KB
      int row = seg * 8 + srow;               // row&7 == srow
      gll16(A  + (size_t)(brow + row) * K + k0 + scol, &As[seg * 512]);
      gll16(Bm + (size_t)(bcol + row) * K + k0 + scol, &Bs[seg * 512]);
    }
    __syncthreads();
#pragma unroll
    for (int ks = 0; ks < 2; ++ks) {
      short8 af[4], bfr[4];
#pragma unroll
      for (int i = 0; i < 4; ++i) {
        int r = wr + i * 16 + l15;            // r&7 == l15&7
        af[i] = *(const short8*)&As[r * 64 + (((ks * 4 + lhi) ^ (l15 & 7)) << 3)];
      }
#pragma unroll
      for (int j = 0; j < 4; ++j) {
        int r = wc + j * 16 + l15;
        bfr[j] = *(const short8*)&Bs[r * 64 + (((ks * 4 + lhi) ^ (l15 & 7)) << 3)];
      }
#pragma unroll
      for (int i = 0; i < 4; ++i)
#pragma unroll
        for (int j = 0; j < 4; ++j) acc[i][j] = mfma16(af[i], bfr[j], acc[i][j]);
    }
  }
  // epilogue: C/D layout col=lane&15, row=(lane>>4)*4+reg  [m89-verified]
#pragma unroll
  for (int i = 0; i < 4; ++i) {
    int r0 = brow + wr + i * 16 + lhi * 4;
#pragma unroll
    for (int j = 0; j < 4; ++j) {
      int c = bcol + wc + j * 16 + l15;
#pragma unroll
      for (int t = 0; t < 4; ++t) {
        float v = acc[i][j][t];
        if constexpr (__is_same(OutT, float)) C[(size_t)(r0 + t) * N + c] = v;
        else                                  C[(size_t)(r0 + t) * N + c] = f2bf(v);
      }
    }
  }
}

// ---------------- RMSNorm + split (f32 math) ----------------
__global__ __launch_bounds__(256) void k_rms(
    const float* __restrict__ comp,   // M x 640 (cols 0..511 latent, 512..575 rope)
    const float* __restrict__ w,      // 512
    short* __restrict__ normed,       // M x 512 bf16
    short* __restrict__ krot)         // M x 64  bf16
{
  __shared__ float red[4];
  const int row = blockIdx.x, tid = threadIdx.x;
  const float* x = comp + (size_t)row * 640;
  float v0 = x[tid], v1 = x[tid + 256];
  float ss = v0 * v0 + v1 * v1;
#pragma unroll
  for (int off = 1; off < 64; off <<= 1) ss += __shfl_xor(ss, off);
  if ((tid & 63) == 0) red[tid >> 6] = ss;
  __syncthreads();
  float rs = rsqrtf((red[0] + red[1] + red[2] + red[3]) * (1.f / 512.f) + 1e-6f);
  normed[(size_t)row * 512 + tid]       = f2bf(w[tid] * v0 * rs);
  normed[(size_t)row * 512 + tid + 256] = f2bf(w[tid + 256] * v1 * rs);
  if (tid < 64) krot[(size_t)row * 64 + tid] = f2bf(x[512 + tid]);
}

// ---------------- V transpose: kv(M,4096) V-half -> vt (B*H, 128, 2048) -----
__global__ __launch_bounds__(256) void k_vtrans(
    const short* __restrict__ kv, short* __restrict__ vt)
{
  __shared__ __align__(16) short t[64][136];   // 272B rows: 16B-aligned
  const int tid = threadIdx.x;
  const int st = blockIdx.x, bh = blockIdx.y;
  const int b = bh >> 4, h = bh & 15;
  const int s0 = st * 64;
#pragma unroll
  for (int i = 0; i < 4; ++i) {
    int e8 = i * 256 + tid;
    int r = e8 >> 4, c = (e8 & 15) * 8;
    short8 v = *(const short8*)&kv[(size_t)(b * S_ + s0 + r) * 4096 + h * 256 + 128 + c];
    *(short8*)&t[r][c] = v;
  }
  __syncthreads();
#pragma unroll
  for (int i = 0; i < 4; ++i) {
    int e8 = i * 256 + tid;
    int d = e8 >> 3, sc = (e8 & 7) * 8;
    short8 o;
#pragma unroll
    for (int k = 0; k < 8; ++k) o[k] = t[sc + k][d];
    *(short8*)&vt[((size_t)bh * 128 + d) * S_ + s0 + sc] = o;
  }
}

// ---------------- causal flash attention (128 q-rows / 8 waves) ----------------
// T14 async-STAGE split: K/V for tile t+1 loaded to REGISTERS during tile t's
// compute; ds_write at top of t+1.
// NOTE: no min-occupancy arg in launch_bounds -- R8 showed `(512,4)` caps the
// allocator at 64 VGPR and spills the 5 loop-carried short8 prefetch regs to
// scratch (WRITE_SIZE 16->288 MB, 2.3x regression). Plain (512) gave 88 VGPR
// with zero spill in R5; +20 prefetch regs fits under the 128 ceiling.
__global__ __launch_bounds__(512) void k_attn(
    const short* __restrict__ q,     // M x 3072  (h*192 + d)
    const short* __restrict__ kv,    // M x 4096  (h*256 + c), c<128 = k_pass
    const short* __restrict__ krot,  // M x 64
    const short* __restrict__ vt,    // (B*H*128) x 2048  (V^T)
    short* __restrict__ outp)        // M x 2048  (h*128 + d)
{
  __shared__ __align__(16) short Kp[64 * 128];
  __shared__ __align__(16) short Kr[64 * 64];
  __shared__ __align__(16) short Vt[128 * 64];
  __shared__ __align__(16) short Ps[128 * 64];

  const int tid = threadIdx.x, lane = tid & 63, wid = tid >> 6;
  const int l15 = lane & 15, lhi = lane >> 4;
  // XCD-co-locating decode: XCD k gets blocks o==k (mod 8) -> bh in [4k,4k+4).
  // Within each bh, qtb descending (LPT).
  const int o = blockIdx.x;
  const int w = (o & 7) * 64 + (o >> 3);
  const int bh = w >> 4;
  const int qtb = 15 - (w & 15);
  const int b = bh >> 4, h = bh & 15;
  const int q0 = qtb * 128;
  const int ktmax = 2 * qtb + 1;

  const int sr8 = lane >> 3;
  const int sc8 = ((lane & 7) ^ sr8) * 8;

  // ---- reg-staged prefetch (T14) ----
  short8 rKp0, rKp1, rKr, rVt0, rVt1;
  const int kpRow  = wid * 8 + (lane >> 4);          // seg(wid*2)*4 + lane>>4
  const int kpCol0 = ((lane & 15) ^ (kpRow & 7)) * 8;
  const int kpRow1 = kpRow + 4;                      // seg(wid*2+1)*4 + lane>>4
  const int kpCol1 = ((lane & 15) ^ (kpRow1 & 7)) * 8;
  const int krRow  = wid * 8 + sr8;
  const int vtD0   = wid * 16 + sr8;                 // seg(wid*2)*8 + sr8
  const int vtD1   = vtD0 + 8;

  auto LOADR = [&](int kt) {
    const int krow0 = b * S_ + kt * 64;
    rKp0 = *(const short8*)(kv + (size_t)(krow0 + kpRow) * 4096 + h * 256 + kpCol0);
    rKp1 = *(const short8*)(kv + (size_t)(krow0 + kpRow1) * 4096 + h * 256 + kpCol1);
    rKr  = *(const short8*)(krot + (size_t)(krow0 + krRow) * 64 + sc8);
    rVt0 = *(const short8*)(vt + ((size_t)bh * 128 + vtD0) * S_ + kt * 64 + sc8);
    rVt1 = *(const short8*)(vt + ((size_t)bh * 128 + vtD1) * S_ + kt * 64 + sc8);
  };
  auto WRITES = [&]() {
    *(short8*)&Kp[(wid * 2) * 512 + lane * 8]     = rKp0;
    *(short8*)&Kp[(wid * 2 + 1) * 512 + lane * 8] = rKp1;
    *(short8*)&Kr[wid * 512 + lane * 8]           = rKr;
    *(short8*)&Vt[(wid * 2) * 512 + lane * 8]     = rVt0;
    *(short8*)&Vt[(wid * 2 + 1) * 512 + lane * 8] = rVt1;
  };

  // Q A-frags: wave strip = wid*16 rows; row-in-strip = l15; k-chunk = lhi*8
  short8 qf[6];
  {
    const short* qp = q + (size_t)(b * S_ + q0 + wid * 16 + l15) * (H_ * QD_) + h * QD_ + lhi * 8;
#pragma unroll
    for (int ks = 0; ks < 6; ++ks) qf[ks] = *(const short8*)(qp + ks * 32);
  }

  float m_run[4] = {-1e30f, -1e30f, -1e30f, -1e30f};
  float l_run[4] = {0.f, 0.f, 0.f, 0.f};
  f32x4 oa[8];
#pragma unroll
  for (int j = 0; j < 8; ++j) oa[j] = (f32x4)0.f;

  const float scale = 0.07216878f;   // 192^-0.5

  LOADR(0);                          // prologue: issue tile-0 loads

  for (int kt = 0; kt <= ktmax; ++kt) {
    // B0: implicit vmcnt(0)+lgkmcnt(0) waits for the prefetched regs (issued a
    // full tile ago -> latency already hidden) and orders prev-tile LDS reads.
    __syncthreads();
    WRITES();                                   // ds_write this tile's K/V
    asm volatile("s_waitcnt lgkmcnt(0)" ::: "memory");  // my writes complete
    if (kt < ktmax) LOADR(kt + 1);              // issue next prefetch (stays in flight)
    __builtin_amdgcn_s_barrier();               // B1: all writes visible; NO vmcnt drain
    __builtin_amdgcn_sched_barrier(0);

    // waves entirely below this tile's k-range skip compute (barriers kept)
    const bool active = (kt * 64) <= (q0 + wid * 16 + 15);

    if (active) {
      // ---- S = Q K^T ----
      f32x4 sf[4];
#pragma unroll
      for (int fc = 0; fc < 4; ++fc) sf[fc] = (f32x4)0.f;
#pragma unroll
      for (int fc = 0; fc < 4; ++fc) {
        int n = fc * 16 + l15, nx = n & 7;
#pragma unroll
        for (int ks = 0; ks < 4; ++ks) {
          short8 kf = *(const short8*)&Kp[n * 128 + (((ks * 4 + lhi) ^ nx) << 3)];
          sf[fc] = mfma16(qf[ks], kf, sf[fc]);
        }
#pragma unroll
        for (int ks = 4; ks < 6; ++ks) {
          short8 kf = *(const short8*)&Kr[n * 64 + ((((ks - 4) * 4 + lhi) ^ nx) << 3)];
          sf[fc] = mfma16(qf[ks], kf, sf[fc]);
        }
      }
      // scale + causal mask (only near-diagonal tiles need the compare)
      if (kt * 64 + 63 > q0 + wid * 16) {
#pragma unroll
        for (int fc = 0; fc < 4; ++fc) {
          int kl = kt * 64 + fc * 16 + l15;
#pragma unroll
          for (int r = 0; r < 4; ++r) {
            int ql = q0 + wid * 16 + lhi * 4 + r;
            sf[fc][r] = (kl <= ql) ? sf[fc][r] * scale : NEGV;
          }
        }
      } else {
#pragma unroll
        for (int fc = 0; fc < 4; ++fc)
#pragma unroll
          for (int r = 0; r < 4; ++r) sf[fc][r] *= scale;
      }
      // ---- online softmax (f32) ----
      float mnew[4], scf[4], rsum[4];
#pragma unroll
      for (int r = 0; r < 4; ++r) {
        float t = fmaxf(fmaxf(sf[0][r], sf[1][r]), fmaxf(sf[2][r], sf[3][r]));
#pragma unroll
        for (int off = 1; off < 16; off <<= 1) t = fmaxf(t, __shfl_xor(t, off));
        mnew[r] = fmaxf(m_run[r], t);
        scf[r] = __expf(m_run[r] - mnew[r]);
        m_run[r] = mnew[r];
        rsum[r] = 0.f;
      }
#pragma unroll
      for (int fc = 0; fc < 4; ++fc)
#pragma unroll
        for (int r = 0; r < 4; ++r) {
          float p = __expf(sf[fc][r] - mnew[r]);
          sf[fc][r] = p;
          rsum[r] += p;
        }
#pragma unroll
      for (int r = 0; r < 4; ++r) {
        float t = rsum[r];
#pragma unroll
        for (int off = 1; off < 16; off <<= 1) t += __shfl_xor(t, off);
        l_run[r] = l_run[r] * scf[r] + t;
      }
#pragma unroll
      for (int j = 0; j < 8; ++j)
#pragma unroll
        for (int r = 0; r < 4; ++r) oa[j][r] *= scf[r];
      // write P (bf16) to LDS, swizzled (rows are WAVE-PRIVATE)
#pragma unroll
      for (int fc = 0; fc < 4; ++fc)
#pragma unroll
        for (int r = 0; r < 4; ++r) {
          int pr = wid * 16 + lhi * 4 + r;
          int pc = fc * 16 + l15;
          Ps[pr * 64 + ((((pc >> 3) ^ (pr & 7)) << 3) | (pc & 7))] = f2bf(sf[fc][r]);
        }
      // wave-local fence only: Ps rows are private to this wave, no block barrier
      asm volatile("s_waitcnt lgkmcnt(0)" ::: "memory");
      __builtin_amdgcn_sched_barrier(0);
      // ---- O += P V ----
      short8 pa[2];
      {
        int prow = wid * 16 + l15, px = prow & 7;
#pragma unroll
        for (int ks = 0; ks < 2; ++ks)
          pa[ks] = *(const short8*)&Ps[prow * 64 + (((ks * 4 + lhi) ^ px) << 3)];
      }
#pragma unroll
      for (int j = 0; j < 8; ++j) {
        int d = j * 16 + l15, dx = d & 7;
#pragma unroll
        for (int ks = 0; ks < 2; ++ks) {
          short8 vb = *(const short8*)&Vt[d * 64 + (((ks * 4 + lhi) ^ dx) << 3)];
          oa[j] = mfma16(pa[ks], vb, oa[j]);
        }
      }
    }
  }
  // epilogue: normalize and store bf16
#pragma unroll
  for (int j = 0; j < 8; ++j)
#pragma unroll
    for (int r = 0; r < 4; ++r) {
      size_t row = (size_t)(b * S_ + q0 + wid * 16 + lhi * 4 + r);
      int col = h * 128 + j * 16 + l15;
      outp[row * 2048 + col] = f2bf(oa[j][r] / l_run[r]);
    }
}

// ---------------- launch ----------------
extern "C" void kernel_launch(void* const* d_in, const int* in_sizes, int n_in,
                              void* d_out, int out_size, void* d_ws, size_t ws_size,
                              hipStream_t stream) {
  const float* hidden = (const float*)d_in[0];
  const float* qw     = (const float*)d_in[1];
  const float* kvaw   = (const float*)d_in[2];
  const float* lnw    = (const float*)d_in[3];
  const float* kvbw   = (const float*)d_in[4];
  const float* ow     = (const float*)d_in[5];

  char* ws = (char*)d_ws;
  short* hidb  = (short*)(ws + 0);           // 4096x2048 bf16   16.78MB
  short* qwb   = (short*)(ws + 16777216);    // 3072x2048        12.58MB
  short* kvawb = (short*)(ws + 29360128);    // 640x2048 (pad)    2.62MB
  short* kvbwb = (short*)(ws + 31981568);    // 4096x512          4.19MB
  short* owb   = (short*)(ws + 36175872);    // 2048x2048         8.39MB
  short* qb    = (short*)(ws + 44564480);    // 4096x3072        25.17MB
  float* comp  = (float*)(ws + 69730304);    // 4096x640 f32     10.49MB
  short* normb = (short*)(ws + 80216064);    // 4096x512          4.19MB
  short* krotb = (short*)(ws + 84410368);    // 4096x64           0.52MB
  short* kvb   = (short*)(ws + 84934656);    // 4096x4096        33.55MB
  short* vtb   = (short*)(ws + 118489088);   // 32x128x2048      16.78MB
  short* attnb = (short*)(ws + 135266304);   // 4096x2048        16.78MB

  // casts
  k_cast4<<<8192, 256, 0, stream>>>(hidden, hidb, 2097152);
  k_cast4<<<6144, 256, 0, stream>>>(qw, qwb, 1572864);
  k_cast_kva<<<1280, 256, 0, stream>>>(kvaw, kvawb);
  k_cast4<<<2048, 256, 0, stream>>>(kvbw, kvbwb, 524288);
  k_cast4<<<4096, 256, 0, stream>>>(ow, owb, 1048576);

  // projections
  k_gemm_bt<short><<<dim3(24, 32), 256, 0, stream>>>(hidb, qwb, qb, M_, 3072, 2048);
  k_gemm_bt<float><<<dim3(5, 32), 256, 0, stream>>>(hidb, kvawb, comp, M_, 640, 2048);
  k_rms<<<4096, 256, 0, stream>>>(comp, lnw, normb, krotb);
  k_gemm_bt<short><<<dim3(32, 32), 256, 0, stream>>>(normb, kvbwb, kvb, M_, 4096, 512);
  k_vtrans<<<dim3(32, 32), 256, 0, stream>>>(kvb, vtb);

  // attention: 512 blocks x 512 threads (8 waves, 128 q-rows each)
  k_attn<<<512, 512, 0, stream>>>(qb, kvb, krotb, vtb, attnb);

  // output projection
  k_gemm_bt<float><<<dim3(16, 32), 256, 0, stream>>>(attnb, owb, (float*)d_out, M_, 2048, 2048);
}